// Round 6
// baseline (785.621 us; speedup 1.0000x reference)
//
#include <hip/hip_runtime.h>
#include <hip/hip_bf16.h>

// Problem constants (fixed by the reference)
#define NNODES 50000
#define NREL   20
#define NSEG   (NNODES * NREL)   // 1,000,000
#define DEMB   64
#define DHID   128

typedef __attribute__((ext_vector_type(8))) short short8;
typedef __attribute__((ext_vector_type(4))) float f32x4;

__device__ __forceinline__ unsigned short bf16rn(float x) {
    unsigned u = __builtin_bit_cast(unsigned, x);
    unsigned r = u + 0x7FFFu + ((u >> 16) & 1u);
    return (unsigned short)(r >> 16);
}
__device__ __forceinline__ float bf16tof(unsigned short h) {
    return __builtin_bit_cast(float, (unsigned)h << 16);
}

// ---------------------------------------------------------------------------
// CSR build: histogram -> exclusive scan (3 kernels) -> placement
// ---------------------------------------------------------------------------

__global__ void hist_kernel(const int* __restrict__ dst, const int* __restrict__ et,
                            int E, int* __restrict__ cnt) {
    for (int e = blockIdx.x * blockDim.x + threadIdx.x; e < E; e += gridDim.x * blockDim.x) {
        atomicAdd(&cnt[dst[e] * NREL + et[e]], 1);
    }
}

__global__ void scan_partial(const int* __restrict__ cnt, int* __restrict__ bsum, int n) {
    __shared__ int s[256];
    int base = blockIdx.x * 1024;
    int t = threadIdx.x;
    int v = 0;
    for (int i = t; i < 1024; i += 256) {
        int idx = base + i;
        v += (idx < n) ? cnt[idx] : 0;
    }
    s[t] = v;
    __syncthreads();
    for (int o = 128; o > 0; o >>= 1) {
        if (t < o) s[t] += s[t + o];
        __syncthreads();
    }
    if (t == 0) bsum[blockIdx.x] = s[0];
}

__global__ void scan_bsums(int* __restrict__ bsum, int nb) {
    __shared__ int s[1024];
    int t = threadIdx.x;
    s[t] = (t < nb) ? bsum[t] : 0;
    __syncthreads();
    for (int o = 1; o < 1024; o <<= 1) {
        int v = (t >= o) ? s[t - o] : 0;
        __syncthreads();
        s[t] += v;
        __syncthreads();
    }
    if (t < nb) bsum[t] = (t == 0) ? 0 : s[t - 1];
}

__global__ void scan_final(const int* __restrict__ cnt, const int* __restrict__ bsum,
                           int* __restrict__ off, int n) {
    __shared__ int s[256];
    int base = blockIdx.x * 1024;
    int t = threadIdx.x;
    int idx = base + t * 4;
    int a0 = (idx + 0 < n) ? cnt[idx + 0] : 0;
    int a1 = (idx + 1 < n) ? cnt[idx + 1] : 0;
    int a2 = (idx + 2 < n) ? cnt[idx + 2] : 0;
    int a3 = (idx + 3 < n) ? cnt[idx + 3] : 0;
    s[t] = a0 + a1 + a2 + a3;
    __syncthreads();
    for (int o = 1; o < 256; o <<= 1) {
        int v = (t >= o) ? s[t - o] : 0;
        __syncthreads();
        s[t] += v;
        __syncthreads();
    }
    int base_ex = ((t == 0) ? 0 : s[t - 1]) + bsum[blockIdx.x];
    if (idx + 0 < n) off[idx + 0] = base_ex;
    if (idx + 1 < n) off[idx + 1] = base_ex + a0;
    if (idx + 2 < n) off[idx + 2] = base_ex + a0 + a1;
    if (idx + 3 < n) off[idx + 3] = base_ex + a0 + a1 + a2;
}

__global__ void place_kernel(const int* __restrict__ src, const int* __restrict__ dst,
                             const int* __restrict__ et, int E,
                             int* __restrict__ off_mut, int* __restrict__ csr_src) {
    for (int e = blockIdx.x * blockDim.x + threadIdx.x; e < E; e += gridDim.x * blockDim.x) {
        int seg = dst[e] * NREL + et[e];
        int p = atomicAdd(&off_mut[seg], 1);
        csr_src[p] = src[e];
    }
}

// ---------------------------------------------------------------------------
// W prep: split f32 W into (hi, lo) bf16 planes, transposed to [col][k],
// k-chunked by 32 with rows padded to 40 shorts.
// Wt layout (shorts): [rel 0..20][kchunk s][plane p][col c][40]
//   chunk stride = 10240 shorts (2 planes x 128 cols x 40); rel 20 == root.
// ---------------------------------------------------------------------------
template <int K>
__global__ void prep_w(const float* __restrict__ W, const float* __restrict__ root,
                       short* __restrict__ Wt) {
    constexpr int KS = K / 32;
    int idx = blockIdx.x * blockDim.x + threadIdx.x;
    int total = (NREL + 1) * 128 * K;
    if (idx >= total) return;
    int r   = idx / (128 * K);
    int rem = idx % (128 * K);
    int c   = rem / K;
    int k   = rem % K;
    float v = (r < NREL) ? W[((size_t)r * K + k) * 128 + c] : root[(size_t)k * 128 + c];
    unsigned short hi = bf16rn(v);
    unsigned short lo = bf16rn(v - bf16tof(hi));
    int s = k >> 5, kk = k & 31;
    size_t base = ((size_t)r * KS + s) * 10240 + (size_t)c * 40 + kk;
    Wt[base]        = (short)hi;
    Wt[base + 5120] = (short)lo;
}

// ---------------------------------------------------------------------------
// Fused RGCN layer v5 (MFMA bf16x3; W from L2; 3 blocks/CU).
// NB=64 nodes/block, 512 threads (8 waves: 2 row-groups x 4 col-groups;
// each wave 32 nodes x 32 cols = 2x2 tiles of 16x16).
// Per relation (+root as rel 20):
//  - 8-lane team per node: gather full-K f32 sums in regs (lane owns a
//    contiguous 64B slice of the row -> coalesced, short8 LDS writes)
//  - per k-half: write (hi,lo) bf16 planes to meanS (18.4 KB), barrier,
//    GEMM with B-fragments read DIRECTLY from global Wt (L2-resident).
// LDS 18.4 KB, launch_bounds(512,6) -> 3 blocks/CU, 782 blocks (3.05/CU).
// ---------------------------------------------------------------------------

template <int K, bool RELU>
__global__ __launch_bounds__(512, 6) void rgcn_layer_kernel(
    const float* __restrict__ X,     // [N][K]
    const short* __restrict__ Wt,    // prepped split W (+root as rel 20)
    const float* __restrict__ bias,  // [128]
    const int* __restrict__ off,     // [NSEG] segment ends
    const int* __restrict__ cnt,     // [NSEG]
    const int* __restrict__ csr_src, // [E]
    float* __restrict__ H,           // [N][128]
    int nnodes)
{
    constexpr int NB  = 64;
    constexpr int FK  = K / 8;         // floats per lane (contiguous slice)
    constexpr int NQ  = FK / 4;        // float4s per lane
    constexpr int NPH = K / 64;        // k-half phases (1 or 2)
    constexpr int KS  = K / 32;        // 32-k chunks in Wt
    constexpr int RSs = 72;            // meanS row stride (shorts): 64 + 8 pad
    constexpr int PS  = NB * RSs;      // plane stride (shorts)

    __shared__ short meanS[2 * PS];    // 18,432 B: one k-half, hi+lo planes

    const int n0 = blockIdx.x * NB;
    const int t  = threadIdx.x;
    const int l  = t & 63;
    const int w  = t >> 6;
    const int rg = w & 1;              // row group: 32 nodes
    const int cg = w >> 1;             // col group: 32 cols
    const int q8 = (l >> 4) * 8;       // k-quarter offset (shorts)

    // gather mapping: 64 teams of 8 lanes, one node per team
    const int team  = t >> 3;
    const int lane8 = t & 7;
    const int node  = n0 + team;

    f32x4 acc[2][2];
    #pragma unroll
    for (int ct = 0; ct < 2; ++ct) {
        const float b = bias[cg * 32 + ct * 16 + (l & 15)];
        #pragma unroll
        for (int rt = 0; rt < 2; ++rt) acc[rt][ct] = (f32x4){b, b, b, b};
    }

    for (int rr = 0; rr <= NREL; ++rr) {
        const short* wtRel = Wt + (size_t)rr * KS * 10240;

        // ---- gather: full-K f32 sums in registers (lane owns 64B slice) ----
        float fs[FK];
        #pragma unroll
        for (int i = 0; i < FK; ++i) fs[i] = 0.0f;

        if (rr < NREL) {
            int c = 0, s0 = 0;
            if (node < nnodes) {
                const int seg = node * NREL + rr;
                c  = cnt[seg];
                s0 = off[seg] - c;
            }
            for (int j = 0; j < c; ++j) {
                const int sv = csr_src[s0 + j];
                const float* xr = X + (size_t)sv * K + lane8 * FK;
                #pragma unroll
                for (int q = 0; q < NQ; ++q) {
                    const float4 v = *(const float4*)&xr[q * 4];
                    fs[q * 4 + 0] += v.x;
                    fs[q * 4 + 1] += v.y;
                    fs[q * 4 + 2] += v.z;
                    fs[q * 4 + 3] += v.w;
                }
            }
            const float inv = 1.0f / (float)max(c, 1);
            #pragma unroll
            for (int i = 0; i < FK; ++i) fs[i] *= inv;
        } else if (node < nnodes) {
            // root pseudo-relation: mean = own row
            const float* xr = X + (size_t)node * K + lane8 * FK;
            #pragma unroll
            for (int q = 0; q < NQ; ++q) {
                const float4 v = *(const float4*)&xr[q * 4];
                fs[q * 4 + 0] = v.x;
                fs[q * 4 + 1] = v.y;
                fs[q * 4 + 2] = v.z;
                fs[q * 4 + 3] = v.w;
            }
        }

        // ---- k-half phases ----
        #pragma unroll
        for (int p = 0; p < NPH; ++p) {
            __syncthreads();   // previous GEMM done reading meanS

            // write this k-half (hi,lo) planes; lane owns contiguous shorts
            if (node < nnodes && (NPH == 1 || (lane8 >> 2) == p)) {
                const int k0   = lane8 * FK - p * 64;   // 0..56, local to k-half
                const int base = team * RSs + k0;
                #pragma unroll
                for (int g = 0; g < FK / 8; ++g) {
                    short8 hi, lo;
                    #pragma unroll
                    for (int i = 0; i < 8; ++i) {
                        const float v = fs[g * 8 + i];
                        const unsigned short h = bf16rn(v);
                        hi[i] = (short)h;
                        lo[i] = (short)bf16rn(v - bf16tof(h));
                    }
                    *(short8*)&meanS[base + g * 8]      = hi;
                    *(short8*)&meanS[PS + base + g * 8] = lo;
                }
            }
            __syncthreads();

            // B-fragments straight from global (L2-resident Wt)
            short8 bhi[2][2], blo[2][2];   // [ls][ct]
            #pragma unroll
            for (int ls = 0; ls < 2; ++ls) {
                #pragma unroll
                for (int ct = 0; ct < 2; ++ct) {
                    const int col = cg * 32 + ct * 16 + (l & 15);
                    const short* bp = wtRel + (size_t)(2 * p + ls) * 10240 + col * 40 + q8;
                    bhi[ls][ct] = *(const short8*)bp;
                    blo[ls][ct] = *(const short8*)(bp + 5120);
                }
            }

            // GEMM this k-half: 3-product bf16 split MFMA
            #pragma unroll
            for (int ls = 0; ls < 2; ++ls) {
                #pragma unroll
                for (int rt = 0; rt < 2; ++rt) {
                    const int row = rg * 32 + rt * 16 + (l & 15);
                    const int ka  = row * RSs + ls * 32 + q8;
                    const short8 a0 = *(const short8*)&meanS[ka];
                    const short8 a1 = *(const short8*)&meanS[PS + ka];
                    #pragma unroll
                    for (int ct = 0; ct < 2; ++ct) {
                        acc[rt][ct] = __builtin_amdgcn_mfma_f32_16x16x32_bf16(a0, bhi[ls][ct], acc[rt][ct], 0, 0, 0);
                        acc[rt][ct] = __builtin_amdgcn_mfma_f32_16x16x32_bf16(a0, blo[ls][ct], acc[rt][ct], 0, 0, 0);
                        acc[rt][ct] = __builtin_amdgcn_mfma_f32_16x16x32_bf16(a1, bhi[ls][ct], acc[rt][ct], 0, 0, 0);
                    }
                }
            }
        }
    }

    // ---- write H: D layout col=lane&15, row=(lane>>4)*4+reg ----
    #pragma unroll
    for (int rt = 0; rt < 2; ++rt) {
        #pragma unroll
        for (int reg = 0; reg < 4; ++reg) {
            const int n = n0 + rg * 32 + rt * 16 + (l >> 4) * 4 + reg;
            if (n < nnodes) {
                #pragma unroll
                for (int ct = 0; ct < 2; ++ct) {
                    float v = acc[rt][ct][reg];
                    if (RELU) v = fmaxf(v, 0.0f);
                    H[(size_t)n * 128 + cg * 32 + ct * 16 + (l & 15)] = v;
                }
            }
        }
    }
}

// ---------------------------------------------------------------------------
// DistMult decoder: one 64-lane wave per batch element
// ---------------------------------------------------------------------------
__global__ void decoder_kernel(const float* __restrict__ H, const float* __restrict__ rel_emb,
                               const int* __restrict__ head, const int* __restrict__ tail,
                               const int* __restrict__ rt, float* __restrict__ out, int B) {
    const int idx  = blockIdx.x * blockDim.x + threadIdx.x;
    const int b    = idx >> 6;
    const int lane = idx & 63;
    if (b >= B) return;
    const float* hp = H + (size_t)head[b] * 128;
    const float* tp = H + (size_t)tail[b] * 128;
    const float* rp = rel_emb + (size_t)rt[b] * 128;
    double s = 0.0;
    #pragma unroll
    for (int c = 0; c < 2; ++c) {
        const int k = lane + c * 64;
        s += (double)hp[k] * (double)rp[k] * (double)tp[k];
    }
    for (int o = 32; o > 0; o >>= 1) s += __shfl_down(s, o);
    if (lane == 0) out[b] = (float)s;
}

// ---------------------------------------------------------------------------

extern "C" void kernel_launch(void* const* d_in, const int* in_sizes, int n_in,
                              void* d_out, int out_size, void* d_ws, size_t ws_size,
                              hipStream_t stream) {
    const int*   edge_index = (const int*)d_in[0];   // [2][E]
    const int*   edge_type  = (const int*)d_in[1];   // [E]
    const int*   head       = (const int*)d_in[2];   // [B]
    const int*   tail       = (const int*)d_in[3];   // [B]
    const int*   rtyp       = (const int*)d_in[4];   // [B]
    const float* node_emb   = (const float*)d_in[5]; // [N][64]
    const float* W1         = (const float*)d_in[6]; // [20][64][128]
    const float* root1      = (const float*)d_in[7]; // [64][128]
    const float* b1         = (const float*)d_in[8]; // [128]
    const float* W2         = (const float*)d_in[9]; // [20][128][128]
    const float* root2      = (const float*)d_in[10];// [128][128]
    const float* b2         = (const float*)d_in[11];// [128]
    const float* rel_emb    = (const float*)d_in[12];// [20][128]
    float* out = (float*)d_out;

    const int E = in_sizes[1];
    const int B = in_sizes[2];
    const int* src = edge_index;
    const int* dst = edge_index + E;

    // workspace carve (all 256B-aligned)
    char* ws = (char*)d_ws;
    size_t o = 0;
    auto carve = [&](size_t bytes) { char* p = ws + o; o += (bytes + 255) & ~size_t(255); return p; };
    int*   off     = (int*)carve(sizeof(int) * NSEG);        // 4 MB
    int*   cnt     = (int*)carve(sizeof(int) * NSEG);        // 4 MB
    int*   csr_src = (int*)carve(sizeof(int) * (size_t)E);   // 6.4 MB
    int*   bsum    = (int*)carve(sizeof(int) * 1024);
    float* h1      = (float*)carve(sizeof(float) * (size_t)NNODES * DHID); // 25.6 MB
    float* h2      = (float*)carve(sizeof(float) * (size_t)NNODES * DHID); // 25.6 MB
    short* Wt1     = (short*)carve(sizeof(short) * (size_t)(NREL + 1) * 2 * 10240); // 1.72 MB
    short* Wt2     = (short*)carve(sizeof(short) * (size_t)(NREL + 1) * 4 * 10240); // 3.44 MB
    (void)ws_size;

    const int NCHUNK = (NSEG + 1023) / 1024;   // 977

    // W prep (independent of CSR; cheap)
    {
        const int tot1 = (NREL + 1) * 128 * DEMB;
        const int tot2 = (NREL + 1) * 128 * DHID;
        prep_w<DEMB><<<(tot1 + 255) / 256, 256, 0, stream>>>(W1, root1, Wt1);
        prep_w<DHID><<<(tot2 + 255) / 256, 256, 0, stream>>>(W2, root2, Wt2);
    }

    // CSR build
    hipMemsetAsync(cnt, 0, sizeof(int) * NSEG, stream);
    hist_kernel<<<2048, 256, 0, stream>>>(dst, edge_type, E, cnt);
    scan_partial<<<NCHUNK, 256, 0, stream>>>(cnt, bsum, NSEG);
    scan_bsums<<<1, 1024, 0, stream>>>(bsum, NCHUNK);
    scan_final<<<NCHUNK, 256, 0, stream>>>(cnt, bsum, off, NSEG);
    place_kernel<<<2048, 256, 0, stream>>>(src, dst, edge_type, E, off, csr_src);

    // layers (64 nodes per block, 512 threads, 3 blocks/CU)
    const int LBLK = (NNODES + 63) / 64;   // 782
    rgcn_layer_kernel<DEMB, true ><<<LBLK, 512, 0, stream>>>(node_emb, Wt1, b1,
                                                             off, cnt, csr_src, h1, NNODES);
    rgcn_layer_kernel<DHID, false><<<LBLK, 512, 0, stream>>>(h1, Wt2, b2,
                                                             off, cnt, csr_src, h2, NNODES);

    // decoder
    decoder_kernel<<<(B * 64 + 255) / 256, 256, 0, stream>>>(h2, rel_emb, head, tail, rtyp, out, B);
}

// Round 7
// 762.287 us; speedup vs baseline: 1.0306x; 1.0306x over previous
//
#include <hip/hip_runtime.h>
#include <hip/hip_bf16.h>

// Problem constants (fixed by the reference)
#define NNODES 50000
#define NREL   20
#define NSEG   (NNODES * NREL)   // 1,000,000
#define DEMB   64
#define DHID   128

typedef __attribute__((ext_vector_type(8))) short short8;
typedef __attribute__((ext_vector_type(4))) float f32x4;

__device__ __forceinline__ unsigned short bf16rn(float x) {
    unsigned u = __builtin_bit_cast(unsigned, x);
    unsigned r = u + 0x7FFFu + ((u >> 16) & 1u);
    return (unsigned short)(r >> 16);
}
__device__ __forceinline__ float bf16tof(unsigned short h) {
    return __builtin_bit_cast(float, (unsigned)h << 16);
}

// ---------------------------------------------------------------------------
// CSR build: histogram -> exclusive scan (3 kernels) -> placement
// ---------------------------------------------------------------------------

__global__ void hist_kernel(const int* __restrict__ dst, const int* __restrict__ et,
                            int E, int* __restrict__ cnt) {
    for (int e = blockIdx.x * blockDim.x + threadIdx.x; e < E; e += gridDim.x * blockDim.x) {
        atomicAdd(&cnt[dst[e] * NREL + et[e]], 1);
    }
}

__global__ void scan_partial(const int* __restrict__ cnt, int* __restrict__ bsum, int n) {
    __shared__ int s[256];
    int base = blockIdx.x * 1024;
    int t = threadIdx.x;
    int v = 0;
    for (int i = t; i < 1024; i += 256) {
        int idx = base + i;
        v += (idx < n) ? cnt[idx] : 0;
    }
    s[t] = v;
    __syncthreads();
    for (int o = 128; o > 0; o >>= 1) {
        if (t < o) s[t] += s[t + o];
        __syncthreads();
    }
    if (t == 0) bsum[blockIdx.x] = s[0];
}

__global__ void scan_bsums(int* __restrict__ bsum, int nb) {
    __shared__ int s[1024];
    int t = threadIdx.x;
    s[t] = (t < nb) ? bsum[t] : 0;
    __syncthreads();
    for (int o = 1; o < 1024; o <<= 1) {
        int v = (t >= o) ? s[t - o] : 0;
        __syncthreads();
        s[t] += v;
        __syncthreads();
    }
    if (t < nb) bsum[t] = (t == 0) ? 0 : s[t - 1];
}

__global__ void scan_final(const int* __restrict__ cnt, const int* __restrict__ bsum,
                           int* __restrict__ off, int n) {
    __shared__ int s[256];
    int base = blockIdx.x * 1024;
    int t = threadIdx.x;
    int idx = base + t * 4;
    int a0 = (idx + 0 < n) ? cnt[idx + 0] : 0;
    int a1 = (idx + 1 < n) ? cnt[idx + 1] : 0;
    int a2 = (idx + 2 < n) ? cnt[idx + 2] : 0;
    int a3 = (idx + 3 < n) ? cnt[idx + 3] : 0;
    s[t] = a0 + a1 + a2 + a3;
    __syncthreads();
    for (int o = 1; o < 256; o <<= 1) {
        int v = (t >= o) ? s[t - o] : 0;
        __syncthreads();
        s[t] += v;
        __syncthreads();
    }
    int base_ex = ((t == 0) ? 0 : s[t - 1]) + bsum[blockIdx.x];
    if (idx + 0 < n) off[idx + 0] = base_ex;
    if (idx + 1 < n) off[idx + 1] = base_ex + a0;
    if (idx + 2 < n) off[idx + 2] = base_ex + a0 + a1;
    if (idx + 3 < n) off[idx + 3] = base_ex + a0 + a1 + a2;
}

__global__ void place_kernel(const int* __restrict__ src, const int* __restrict__ dst,
                             const int* __restrict__ et, int E,
                             int* __restrict__ off_mut, int* __restrict__ csr_src) {
    for (int e = blockIdx.x * blockDim.x + threadIdx.x; e < E; e += gridDim.x * blockDim.x) {
        int seg = dst[e] * NREL + et[e];
        int p = atomicAdd(&off_mut[seg], 1);
        csr_src[p] = src[e];
    }
}

// ---------------------------------------------------------------------------
// W prep: split f32 W into (hi, lo) bf16 planes, transposed to [col][k],
// k-chunked by 32 with rows padded to 40 shorts.
// Wt layout (shorts): [rel 0..20][kchunk s][plane p][col c][40]
//   chunk stride = 10240 shorts (2 planes x 128 cols x 40); rel 20 == root.
// ---------------------------------------------------------------------------
template <int K>
__global__ void prep_w(const float* __restrict__ W, const float* __restrict__ root,
                       short* __restrict__ Wt) {
    constexpr int KS = K / 32;
    int idx = blockIdx.x * blockDim.x + threadIdx.x;
    int total = (NREL + 1) * 128 * K;
    if (idx >= total) return;
    int r   = idx / (128 * K);
    int rem = idx % (128 * K);
    int c   = rem / K;
    int k   = rem % K;
    float v = (r < NREL) ? W[((size_t)r * K + k) * 128 + c] : root[(size_t)k * 128 + c];
    unsigned short hi = bf16rn(v);
    unsigned short lo = bf16rn(v - bf16tof(hi));
    int s = k >> 5, kk = k & 31;
    size_t base = ((size_t)r * KS + s) * 10240 + (size_t)c * 40 + kk;
    Wt[base]        = (short)hi;
    Wt[base + 5120] = (short)lo;
}

// ---------------------------------------------------------------------------
// Fused RGCN layer v6 (MFMA bf16x3; k-QUARTER phased LDS = 41 KB;
// relation-split x2 across gridDim.y with f32 atomicAdd combine).
// NB=128 nodes/block, 512 threads (8 waves: 4 row-groups x 2 col-groups;
// wave = 32 nodes x 64 cols = 2x4 tiles of 16x16).
// Per relation in this block's split (+root as rel 20 in split 1):
//  - stage W chunk0 async (lands under gather)
//  - dual-node branchless gather: full-K f32 sums in registers
//  - per k-quarter q: [q>0: barrier + stage chunk q], write quarter to
//    meanS (hi/lo bf16), barrier (drains vmcnt), GEMM with staged Wbuf.
// Layer-1 ReLU is applied on READ (RELU_IN) by layer 2 / not at write.
// ---------------------------------------------------------------------------

__device__ __forceinline__ void stage20(const short* __restrict__ gsrc,
                                        short* ldst, int t) {
    const int u = t >> 6, lane = t & 63;
    #pragma unroll
    for (int j = 0; j < 3; ++j) {
        int blk = u + j * 8;
        if (blk >= 20) break;   // 20 KB = 20 blocks of 1KB
        __builtin_amdgcn_global_load_lds(
            (const __attribute__((address_space(1))) void*)((const char*)gsrc + blk * 1024 + lane * 16),
            (__attribute__((address_space(3))) void*)((char*)ldst + blk * 1024 + lane * 16),
            16, 0, 0);
    }
}

template <int K, bool RELU_IN>
__global__ __launch_bounds__(512, 4) void rgcn_layer_kernel(
    const float* __restrict__ X,     // [N][K]
    const short* __restrict__ Wt,    // prepped split W (+root as rel 20)
    const float* __restrict__ bias,  // [128]
    const int* __restrict__ off,     // [NSEG] segment ends
    const int* __restrict__ cnt,     // [NSEG]
    const int* __restrict__ csr_src, // [E]
    float* __restrict__ H,           // [N][128], zero-initialized; atomic accum
    int nnodes)
{
    constexpr int NB  = 128;
    constexpr int NQ  = K / 32;        // float4s per lane per row (strided)
    constexpr int KS  = K / 32;        // 32-k chunks / quarters
    constexpr int QSs = 40;            // meanS row stride per quarter (shorts)
    constexpr int PSq = NB * QSs;      // 5120 shorts: one plane of one quarter

    __shared__ short meanS[2 * PSq];   // 20,480 B (quarter, hi+lo planes)
    __shared__ short Wbuf[10240];      // 20,480 B (one 32-k chunk, 2 planes)

    const int n0 = blockIdx.x * NB;
    const int ry = blockIdx.y;         // relation split: 0 -> rels 0..10, 1 -> 11..20
    const int t  = threadIdx.x;
    const int l  = t & 63;
    const int w  = t >> 6;
    const int rg = w & 3;              // row group: 32 nodes
    const int cg = w >> 2;             // col group: 64 cols
    const int q8 = (l >> 4) * 8;       // k-quarter-frag offset (shorts)

    // gather mapping: 64 teams of 8 lanes; team handles nodes {team, team+64}
    const int team  = t >> 3;
    const int lane8 = t & 7;

    f32x4 acc[2][4];
    #pragma unroll
    for (int ct = 0; ct < 4; ++ct) {
        const float b = (ry == 0) ? bias[cg * 64 + ct * 16 + (l & 15)] : 0.0f;
        #pragma unroll
        for (int rt = 0; rt < 2; ++rt) acc[rt][ct] = (f32x4){b, b, b, b};
    }

    const int r0 = ry ? 11 : 0;
    const int r1 = ry ? 21 : 11;       // rr==20 is the root pseudo-relation

    for (int rr = r0; rr < r1; ++rr) {
        __syncthreads();   // prev relation's last GEMM done (Wbuf+meanS free)

        const short* wtRel = Wt + (size_t)rr * KS * 10240;
        stage20(wtRel, Wbuf, t);       // chunk 0; lands under the gather

        // ---- dual-node branchless gather: full-K f32 sums in registers ----
        const int nA = n0 + team;
        const int nB = n0 + team + 64;
        float sAx[NQ], sAy[NQ], sAz[NQ], sAw[NQ];
        float sBx[NQ], sBy[NQ], sBz[NQ], sBw[NQ];
        #pragma unroll
        for (int q = 0; q < NQ; ++q) {
            sAx[q] = sAy[q] = sAz[q] = sAw[q] = 0.f;
            sBx[q] = sBy[q] = sBz[q] = sBw[q] = 0.f;
        }

        if (rr < NREL) {
            int cA = 0, oA = 0, cB = 0, oB = 0;
            if (nA < nnodes) { const int sg = nA * NREL + rr; cA = cnt[sg]; oA = off[sg] - cA; }
            if (nB < nnodes) { const int sg = nB * NREL + rr; cB = cnt[sg]; oB = off[sg] - cB; }
            const int jmax = max(cA, cB);
            for (int j = 0; j < jmax; ++j) {
                const bool pa = j < cA, pb = j < cB;
                const int ia = csr_src[pa ? (oA + j) : 0];
                const int ib = csr_src[pb ? (oB + j) : 0];
                const float* pxA = X + (size_t)ia * K;
                const float* pxB = X + (size_t)ib * K;
                float4 vA[NQ], vB[NQ];
                #pragma unroll
                for (int q = 0; q < NQ; ++q) vA[q] = *(const float4*)&pxA[q * 32 + lane8 * 4];
                #pragma unroll
                for (int q = 0; q < NQ; ++q) vB[q] = *(const float4*)&pxB[q * 32 + lane8 * 4];
                if (RELU_IN) {
                    #pragma unroll
                    for (int q = 0; q < NQ; ++q) {
                        vA[q].x = fmaxf(vA[q].x, 0.f); vA[q].y = fmaxf(vA[q].y, 0.f);
                        vA[q].z = fmaxf(vA[q].z, 0.f); vA[q].w = fmaxf(vA[q].w, 0.f);
                        vB[q].x = fmaxf(vB[q].x, 0.f); vB[q].y = fmaxf(vB[q].y, 0.f);
                        vB[q].z = fmaxf(vB[q].z, 0.f); vB[q].w = fmaxf(vB[q].w, 0.f);
                    }
                }
                if (pa) {
                    #pragma unroll
                    for (int q = 0; q < NQ; ++q) {
                        sAx[q] += vA[q].x; sAy[q] += vA[q].y; sAz[q] += vA[q].z; sAw[q] += vA[q].w;
                    }
                }
                if (pb) {
                    #pragma unroll
                    for (int q = 0; q < NQ; ++q) {
                        sBx[q] += vB[q].x; sBy[q] += vB[q].y; sBz[q] += vB[q].z; sBw[q] += vB[q].w;
                    }
                }
            }
            const float invA = 1.0f / (float)max(cA, 1);
            const float invB = 1.0f / (float)max(cB, 1);
            #pragma unroll
            for (int q = 0; q < NQ; ++q) {
                sAx[q] *= invA; sAy[q] *= invA; sAz[q] *= invA; sAw[q] *= invA;
                sBx[q] *= invB; sBy[q] *= invB; sBz[q] *= invB; sBw[q] *= invB;
            }
        } else {
            // root pseudo-relation: mean = own row (relu'd if RELU_IN)
            if (nA < nnodes) {
                const float* xr = X + (size_t)nA * K;
                #pragma unroll
                for (int q = 0; q < NQ; ++q) {
                    float4 v = *(const float4*)&xr[q * 32 + lane8 * 4];
                    if (RELU_IN) { v.x = fmaxf(v.x, 0.f); v.y = fmaxf(v.y, 0.f);
                                   v.z = fmaxf(v.z, 0.f); v.w = fmaxf(v.w, 0.f); }
                    sAx[q] = v.x; sAy[q] = v.y; sAz[q] = v.z; sAw[q] = v.w;
                }
            }
            if (nB < nnodes) {
                const float* xr = X + (size_t)nB * K;
                #pragma unroll
                for (int q = 0; q < NQ; ++q) {
                    float4 v = *(const float4*)&xr[q * 32 + lane8 * 4];
                    if (RELU_IN) { v.x = fmaxf(v.x, 0.f); v.y = fmaxf(v.y, 0.f);
                                   v.z = fmaxf(v.z, 0.f); v.w = fmaxf(v.w, 0.f); }
                    sBx[q] = v.x; sBy[q] = v.y; sBz[q] = v.z; sBw[q] = v.w;
                }
            }
        }

        // ---- k-quarter phases ----
        #pragma unroll
        for (int q = 0; q < KS; ++q) {
            if (q > 0) {
                __syncthreads();                       // GEMM q-1 done with Wbuf/meanS
                stage20(wtRel + q * 10240, Wbuf, t);   // chunk q
            }
            // write quarter q (hi,lo) planes: lane owns float4 at k lane8*4
            {
                const int kb = lane8 * 4;
                {
                    const float vx = sAx[q], vy = sAy[q], vz = sAz[q], vw = sAw[q];
                    const unsigned short hx = bf16rn(vx), hy = bf16rn(vy), hz = bf16rn(vz), hw = bf16rn(vw);
                    short4 hi4, lo4;
                    hi4.x = (short)hx; hi4.y = (short)hy; hi4.z = (short)hz; hi4.w = (short)hw;
                    lo4.x = (short)bf16rn(vx - bf16tof(hx));
                    lo4.y = (short)bf16rn(vy - bf16tof(hy));
                    lo4.z = (short)bf16rn(vz - bf16tof(hz));
                    lo4.w = (short)bf16rn(vw - bf16tof(hw));
                    *(short4*)&meanS[team * QSs + kb]       = hi4;
                    *(short4*)&meanS[PSq + team * QSs + kb] = lo4;
                }
                {
                    const float vx = sBx[q], vy = sBy[q], vz = sBz[q], vw = sBw[q];
                    const unsigned short hx = bf16rn(vx), hy = bf16rn(vy), hz = bf16rn(vz), hw = bf16rn(vw);
                    short4 hi4, lo4;
                    hi4.x = (short)hx; hi4.y = (short)hy; hi4.z = (short)hz; hi4.w = (short)hw;
                    lo4.x = (short)bf16rn(vx - bf16tof(hx));
                    lo4.y = (short)bf16rn(vy - bf16tof(hy));
                    lo4.z = (short)bf16rn(vz - bf16tof(hz));
                    lo4.w = (short)bf16rn(vw - bf16tof(hw));
                    *(short4*)&meanS[(team + 64) * QSs + kb]       = hi4;
                    *(short4*)&meanS[PSq + (team + 64) * QSs + kb] = lo4;
                }
            }
            __syncthreads();   // drains vmcnt (Wbuf chunk q landed) + lgkm

            // B-fragments from staged Wbuf (reused across both row-tiles)
            short8 bhi[4], blo[4];
            #pragma unroll
            for (int ct = 0; ct < 4; ++ct) {
                const int col = cg * 64 + ct * 16 + (l & 15);
                bhi[ct] = *(const short8*)&Wbuf[       col * 40 + q8];
                blo[ct] = *(const short8*)&Wbuf[5120 + col * 40 + q8];
            }

            // GEMM quarter q: 3-product bf16 split MFMA
            #pragma unroll
            for (int rt = 0; rt < 2; ++rt) {
                const int row = rg * 32 + rt * 16 + (l & 15);
                const int ka  = row * QSs + q8;
                const short8 a0 = *(const short8*)&meanS[ka];
                const short8 a1 = *(const short8*)&meanS[PSq + ka];
                #pragma unroll
                for (int ct = 0; ct < 4; ++ct) {
                    acc[rt][ct] = __builtin_amdgcn_mfma_f32_16x16x32_bf16(a0, bhi[ct], acc[rt][ct], 0, 0, 0);
                    acc[rt][ct] = __builtin_amdgcn_mfma_f32_16x16x32_bf16(a0, blo[ct], acc[rt][ct], 0, 0, 0);
                    acc[rt][ct] = __builtin_amdgcn_mfma_f32_16x16x32_bf16(a1, bhi[ct], acc[rt][ct], 0, 0, 0);
                }
            }
        }
    }

    // ---- combine partials: atomicAdd into zero-initialized H ----
    // D layout: col=lane&15, row=(lane>>4)*4+reg
    #pragma unroll
    for (int rt = 0; rt < 2; ++rt) {
        #pragma unroll
        for (int reg = 0; reg < 4; ++reg) {
            const int node = n0 + rg * 32 + rt * 16 + (l >> 4) * 4 + reg;
            if (node < nnodes) {
                #pragma unroll
                for (int ct = 0; ct < 4; ++ct) {
                    atomicAdd(&H[(size_t)node * 128 + cg * 64 + ct * 16 + (l & 15)],
                              acc[rt][ct][reg]);
                }
            }
        }
    }
}

// ---------------------------------------------------------------------------
// DistMult decoder: one 64-lane wave per batch element (h2 has no relu)
// ---------------------------------------------------------------------------
__global__ void decoder_kernel(const float* __restrict__ H, const float* __restrict__ rel_emb,
                               const int* __restrict__ head, const int* __restrict__ tail,
                               const int* __restrict__ rt, float* __restrict__ out, int B) {
    const int idx  = blockIdx.x * blockDim.x + threadIdx.x;
    const int b    = idx >> 6;
    const int lane = idx & 63;
    if (b >= B) return;
    const float* hp = H + (size_t)head[b] * 128;
    const float* tp = H + (size_t)tail[b] * 128;
    const float* rp = rel_emb + (size_t)rt[b] * 128;
    double s = 0.0;
    #pragma unroll
    for (int c = 0; c < 2; ++c) {
        const int k = lane + c * 64;
        s += (double)hp[k] * (double)rp[k] * (double)tp[k];
    }
    for (int o = 32; o > 0; o >>= 1) s += __shfl_down(s, o);
    if (lane == 0) out[b] = (float)s;
}

// ---------------------------------------------------------------------------

extern "C" void kernel_launch(void* const* d_in, const int* in_sizes, int n_in,
                              void* d_out, int out_size, void* d_ws, size_t ws_size,
                              hipStream_t stream) {
    const int*   edge_index = (const int*)d_in[0];   // [2][E]
    const int*   edge_type  = (const int*)d_in[1];   // [E]
    const int*   head       = (const int*)d_in[2];   // [B]
    const int*   tail       = (const int*)d_in[3];   // [B]
    const int*   rtyp       = (const int*)d_in[4];   // [B]
    const float* node_emb   = (const float*)d_in[5]; // [N][64]
    const float* W1         = (const float*)d_in[6]; // [20][64][128]
    const float* root1      = (const float*)d_in[7]; // [64][128]
    const float* b1         = (const float*)d_in[8]; // [128]
    const float* W2         = (const float*)d_in[9]; // [20][128][128]
    const float* root2      = (const float*)d_in[10];// [128][128]
    const float* b2         = (const float*)d_in[11];// [128]
    const float* rel_emb    = (const float*)d_in[12];// [20][128]
    float* out = (float*)d_out;

    const int E = in_sizes[1];
    const int B = in_sizes[2];
    const int* src = edge_index;
    const int* dst = edge_index + E;

    // workspace carve (all 256B-aligned)
    char* ws = (char*)d_ws;
    size_t o = 0;
    auto carve = [&](size_t bytes) { char* p = ws + o; o += (bytes + 255) & ~size_t(255); return p; };
    int*   off     = (int*)carve(sizeof(int) * NSEG);        // 4 MB
    int*   cnt     = (int*)carve(sizeof(int) * NSEG);        // 4 MB
    int*   csr_src = (int*)carve(sizeof(int) * (size_t)E);   // 6.4 MB
    int*   bsum    = (int*)carve(sizeof(int) * 1024);
    float* h1      = (float*)carve(sizeof(float) * (size_t)NNODES * DHID); // 25.6 MB
    float* h2      = (float*)carve(sizeof(float) * (size_t)NNODES * DHID); // 25.6 MB
    short* Wt1     = (short*)carve(sizeof(short) * (size_t)(NREL + 1) * 2 * 10240); // 1.72 MB
    short* Wt2     = (short*)carve(sizeof(short) * (size_t)(NREL + 1) * 4 * 10240); // 3.44 MB
    (void)ws_size;

    const int NCHUNK = (NSEG + 1023) / 1024;   // 977

    // W prep (independent of CSR; cheap)
    {
        const int tot1 = (NREL + 1) * 128 * DEMB;
        const int tot2 = (NREL + 1) * 128 * DHID;
        prep_w<DEMB><<<(tot1 + 255) / 256, 256, 0, stream>>>(W1, root1, Wt1);
        prep_w<DHID><<<(tot2 + 255) / 256, 256, 0, stream>>>(W2, root2, Wt2);
    }

    // CSR build
    hipMemsetAsync(cnt, 0, sizeof(int) * NSEG, stream);
    hist_kernel<<<2048, 256, 0, stream>>>(dst, edge_type, E, cnt);
    scan_partial<<<NCHUNK, 256, 0, stream>>>(cnt, bsum, NSEG);
    scan_bsums<<<1, 1024, 0, stream>>>(bsum, NCHUNK);
    scan_final<<<NCHUNK, 256, 0, stream>>>(cnt, bsum, off, NSEG);
    place_kernel<<<2048, 256, 0, stream>>>(src, dst, edge_type, E, off, csr_src);

    // zero-init layer outputs (atomic accumulation targets)
    hipMemsetAsync(h1, 0, sizeof(float) * (size_t)NNODES * DHID, stream);
    hipMemsetAsync(h2, 0, sizeof(float) * (size_t)NNODES * DHID, stream);

    // layers: 128 nodes/block, 512 threads, relation-split x2 (gridDim.y)
    const dim3 LGRID((NNODES + 127) / 128, 2);   // 391 x 2 = 782 blocks
    rgcn_layer_kernel<DEMB, false><<<LGRID, 512, 0, stream>>>(node_emb, Wt1, b1,
                                                              off, cnt, csr_src, h1, NNODES);
    rgcn_layer_kernel<DHID, true ><<<LGRID, 512, 0, stream>>>(h1, Wt2, b2,
                                                              off, cnt, csr_src, h2, NNODES);

    // decoder
    decoder_kernel<<<(B * 64 + 255) / 256, 256, 0, stream>>>(h2, rel_emb, head, tail, rtyp, out, B);
}

// Round 8
// 687.145 us; speedup vs baseline: 1.1433x; 1.1094x over previous
//
#include <hip/hip_runtime.h>
#include <hip/hip_bf16.h>

// Problem constants (fixed by the reference)
#define NNODES 50000
#define NREL   20
#define NSEG   (NNODES * NREL)   // 1,000,000
#define DEMB   64
#define DHID   128

typedef __attribute__((ext_vector_type(8))) short short8;
typedef __attribute__((ext_vector_type(4))) float f32x4;

__device__ __forceinline__ unsigned short bf16rn(float x) {
    unsigned u = __builtin_bit_cast(unsigned, x);
    unsigned r = u + 0x7FFFu + ((u >> 16) & 1u);
    return (unsigned short)(r >> 16);
}
__device__ __forceinline__ float bf16tof(unsigned short h) {
    return __builtin_bit_cast(float, (unsigned)h << 16);
}

// ---------------------------------------------------------------------------
// CSR build: histogram -> exclusive scan (3 kernels) -> placement
// ---------------------------------------------------------------------------

__global__ void hist_kernel(const int* __restrict__ dst, const int* __restrict__ et,
                            int E, int* __restrict__ cnt) {
    for (int e = blockIdx.x * blockDim.x + threadIdx.x; e < E; e += gridDim.x * blockDim.x) {
        atomicAdd(&cnt[dst[e] * NREL + et[e]], 1);
    }
}

__global__ void scan_partial(const int* __restrict__ cnt, int* __restrict__ bsum, int n) {
    __shared__ int s[256];
    int base = blockIdx.x * 1024;
    int t = threadIdx.x;
    int v = 0;
    for (int i = t; i < 1024; i += 256) {
        int idx = base + i;
        v += (idx < n) ? cnt[idx] : 0;
    }
    s[t] = v;
    __syncthreads();
    for (int o = 128; o > 0; o >>= 1) {
        if (t < o) s[t] += s[t + o];
        __syncthreads();
    }
    if (t == 0) bsum[blockIdx.x] = s[0];
}

__global__ void scan_bsums(int* __restrict__ bsum, int nb) {
    __shared__ int s[1024];
    int t = threadIdx.x;
    s[t] = (t < nb) ? bsum[t] : 0;
    __syncthreads();
    for (int o = 1; o < 1024; o <<= 1) {
        int v = (t >= o) ? s[t - o] : 0;
        __syncthreads();
        s[t] += v;
        __syncthreads();
    }
    if (t < nb) bsum[t] = (t == 0) ? 0 : s[t - 1];
}

__global__ void scan_final(const int* __restrict__ cnt, const int* __restrict__ bsum,
                           int* __restrict__ off, int n) {
    __shared__ int s[256];
    int base = blockIdx.x * 1024;
    int t = threadIdx.x;
    int idx = base + t * 4;
    int a0 = (idx + 0 < n) ? cnt[idx + 0] : 0;
    int a1 = (idx + 1 < n) ? cnt[idx + 1] : 0;
    int a2 = (idx + 2 < n) ? cnt[idx + 2] : 0;
    int a3 = (idx + 3 < n) ? cnt[idx + 3] : 0;
    s[t] = a0 + a1 + a2 + a3;
    __syncthreads();
    for (int o = 1; o < 256; o <<= 1) {
        int v = (t >= o) ? s[t - o] : 0;
        __syncthreads();
        s[t] += v;
        __syncthreads();
    }
    int base_ex = ((t == 0) ? 0 : s[t - 1]) + bsum[blockIdx.x];
    if (idx + 0 < n) off[idx + 0] = base_ex;
    if (idx + 1 < n) off[idx + 1] = base_ex + a0;
    if (idx + 2 < n) off[idx + 2] = base_ex + a0 + a1;
    if (idx + 3 < n) off[idx + 3] = base_ex + a0 + a1 + a2;
}

__global__ void place_kernel(const int* __restrict__ src, const int* __restrict__ dst,
                             const int* __restrict__ et, int E,
                             int* __restrict__ off_mut, int* __restrict__ csr_src) {
    for (int e = blockIdx.x * blockDim.x + threadIdx.x; e < E; e += gridDim.x * blockDim.x) {
        int seg = dst[e] * NREL + et[e];
        int p = atomicAdd(&off_mut[seg], 1);
        csr_src[p] = src[e];
    }
}

// ---------------------------------------------------------------------------
// W prep: split f32 W into (hi, lo) bf16 planes, transposed to [col][k],
// k-chunked by 32 with rows padded to 40 shorts.
// Wt layout (shorts): [rel 0..20][kchunk s][plane p][col c][40]
//   chunk stride = 10240 shorts (2 planes x 128 cols x 40); rel 20 == root.
// ---------------------------------------------------------------------------
template <int K>
__global__ void prep_w(const float* __restrict__ W, const float* __restrict__ root,
                       short* __restrict__ Wt) {
    constexpr int KS = K / 32;
    int idx = blockIdx.x * blockDim.x + threadIdx.x;
    int total = (NREL + 1) * 128 * K;
    if (idx >= total) return;
    int r   = idx / (128 * K);
    int rem = idx % (128 * K);
    int c   = rem / K;
    int k   = rem % K;
    float v = (r < NREL) ? W[((size_t)r * K + k) * 128 + c] : root[(size_t)k * 128 + c];
    unsigned short hi = bf16rn(v);
    unsigned short lo = bf16rn(v - bf16tof(hi));
    int s = k >> 5, kk = k & 31;
    size_t base = ((size_t)r * KS + s) * 10240 + (size_t)c * 40 + kk;
    Wt[base]        = (short)hi;
    Wt[base + 5120] = (short)lo;
}

// ---------------------------------------------------------------------------
// Fused RGCN layer v7 (MFMA bf16x3; fine-grained: NB=32 nodes, 256 threads,
// relation-split x2, edge-unroll x3, cnt/off LDS-preload, 56-short stride).
// 4 waves per block; wave w owns cols [w*32, w*32+32), all 32 nodes
// (2 row-tiles x 2 col-tiles of 16x16). Gather: 32 teams of 8 lanes, one
// node each, 3 edges in flight (12 float4 row-loads per lane).
// Per relation: stage W chunk0 (global_load_lds, lands under gather);
// per k-quarter: write (hi,lo) bf16 quarter to meanS, barrier, GEMM.
// Partials combined by f32 atomicAdd into zero-initialized H.
// ---------------------------------------------------------------------------

__device__ __forceinline__ void stage20(const short* __restrict__ gsrc,
                                        short* ldst, int t) {
    const int u = t >> 6, lane = t & 63;   // 4 waves x 5 x 1KB = 20KB
    #pragma unroll
    for (int j = 0; j < 5; ++j) {
        const int blk = u + j * 4;
        __builtin_amdgcn_global_load_lds(
            (const __attribute__((address_space(1))) void*)((const char*)gsrc + blk * 1024 + lane * 16),
            (__attribute__((address_space(3))) void*)((char*)ldst + blk * 1024 + lane * 16),
            16, 0, 0);
    }
}

template <int K, bool RELU_IN>
__global__ __launch_bounds__(256, 4) void rgcn_layer_kernel(
    const float* __restrict__ X,     // [N][K]
    const short* __restrict__ Wt,    // prepped split W (+root as rel 20)
    const float* __restrict__ bias,  // [128]
    const int* __restrict__ off,     // [NSEG] segment ends
    const int* __restrict__ cnt,     // [NSEG]
    const int* __restrict__ csr_src, // [E]
    float* __restrict__ H,           // [N][128], zero-initialized; atomic accum
    int nnodes)
{
    constexpr int NB  = 32;
    constexpr int NQ  = K / 32;        // float4s per lane per row (strided)
    constexpr int KS  = K / 32;        // 32-k quarters
    constexpr int QSs = 56;            // meanS row stride (shorts): 7x16B, odd granule
    constexpr int PSq = NB * QSs;      // 1792 shorts: one plane of one quarter

    __shared__ short          meanS[2 * PSq];      // 7,168 B
    __shared__ short          Wbuf[10240];         // 20,480 B
    __shared__ unsigned short cntS[NB * NREL];     // 1,280 B
    __shared__ int            offS[NB * NREL];     // 2,560 B

    const int n0 = blockIdx.x * NB;
    const int ry = blockIdx.y;         // 0 -> rels 0..10, 1 -> rels 11..19 + root
    const int t  = threadIdx.x;
    const int l  = t & 63;
    const int wv = t >> 6;             // wave id 0..3: col group of 32
    const int q8 = (l >> 4) * 8;       // k-slot offset (shorts)

    // gather mapping: 32 teams of 8 lanes, one node each
    const int team  = t >> 3;
    const int lane8 = t & 7;
    const int node  = n0 + team;

    // ---- preload cnt/off for this block's 32 nodes, all rels (coalesced) ----
    {
        const int base = n0 * NREL;
        for (int i = t; i < NB * NREL; i += 256) {
            const int nn = n0 + i / NREL;
            int vc = 0, vo = 0;
            if (nn < nnodes) { vc = cnt[base + i]; vo = off[base + i]; }
            cntS[i] = (unsigned short)vc;
            offS[i] = vo;
        }
    }

    f32x4 acc[2][2];
    #pragma unroll
    for (int ct = 0; ct < 2; ++ct) {
        const float b = (ry == 0) ? bias[wv * 32 + ct * 16 + (l & 15)] : 0.0f;
        #pragma unroll
        for (int rt = 0; rt < 2; ++rt) acc[rt][ct] = (f32x4){b, b, b, b};
    }

    const int r0 = ry ? 11 : 0;
    const int r1 = ry ? 21 : 11;       // rr==20 is the root pseudo-relation

    for (int rr = r0; rr < r1; ++rr) {
        __syncthreads();   // prev relation's last GEMM done; preload visible (rr==r0)

        const short* wtRel = Wt + (size_t)rr * KS * 10240;
        stage20(wtRel, Wbuf, t);       // chunk 0; lands under the gather

        // ---- gather: full-K f32 sums in registers, 3 edges in flight ----
        float sx[NQ], sy[NQ], sz[NQ], sw[NQ];
        #pragma unroll
        for (int q = 0; q < NQ; ++q) { sx[q] = sy[q] = sz[q] = sw[q] = 0.f; }

        if (rr < NREL) {
            const int c  = cntS[team * NREL + rr];
            const int s0 = offS[team * NREL + rr] - c;
            for (int j = 0; j < c; j += 3) {
                const int e1 = min(j + 1, c - 1);
                const int e2 = min(j + 2, c - 1);
                const int i0 = csr_src[s0 + j];
                const int i1 = csr_src[s0 + e1];
                const int i2 = csr_src[s0 + e2];
                const float* p0 = X + (size_t)i0 * K + lane8 * 4;
                const float* p1 = X + (size_t)i1 * K + lane8 * 4;
                const float* p2 = X + (size_t)i2 * K + lane8 * 4;
                float4 v0[NQ], v1[NQ], v2[NQ];
                #pragma unroll
                for (int q = 0; q < NQ; ++q) v0[q] = *(const float4*)&p0[q * 32];
                #pragma unroll
                for (int q = 0; q < NQ; ++q) v1[q] = *(const float4*)&p1[q * 32];
                #pragma unroll
                for (int q = 0; q < NQ; ++q) v2[q] = *(const float4*)&p2[q * 32];
                if (RELU_IN) {
                    #pragma unroll
                    for (int q = 0; q < NQ; ++q) {
                        v0[q].x = fmaxf(v0[q].x, 0.f); v0[q].y = fmaxf(v0[q].y, 0.f);
                        v0[q].z = fmaxf(v0[q].z, 0.f); v0[q].w = fmaxf(v0[q].w, 0.f);
                        v1[q].x = fmaxf(v1[q].x, 0.f); v1[q].y = fmaxf(v1[q].y, 0.f);
                        v1[q].z = fmaxf(v1[q].z, 0.f); v1[q].w = fmaxf(v1[q].w, 0.f);
                        v2[q].x = fmaxf(v2[q].x, 0.f); v2[q].y = fmaxf(v2[q].y, 0.f);
                        v2[q].z = fmaxf(v2[q].z, 0.f); v2[q].w = fmaxf(v2[q].w, 0.f);
                    }
                }
                #pragma unroll
                for (int q = 0; q < NQ; ++q) {
                    sx[q] += v0[q].x; sy[q] += v0[q].y; sz[q] += v0[q].z; sw[q] += v0[q].w;
                }
                if (j + 1 < c) {
                    #pragma unroll
                    for (int q = 0; q < NQ; ++q) {
                        sx[q] += v1[q].x; sy[q] += v1[q].y; sz[q] += v1[q].z; sw[q] += v1[q].w;
                    }
                }
                if (j + 2 < c) {
                    #pragma unroll
                    for (int q = 0; q < NQ; ++q) {
                        sx[q] += v2[q].x; sy[q] += v2[q].y; sz[q] += v2[q].z; sw[q] += v2[q].w;
                    }
                }
            }
            const float inv = 1.0f / (float)max(c, 1);
            #pragma unroll
            for (int q = 0; q < NQ; ++q) { sx[q] *= inv; sy[q] *= inv; sz[q] *= inv; sw[q] *= inv; }
        } else if (node < nnodes) {
            // root pseudo-relation: mean = own row (relu'd if RELU_IN)
            const float* xr = X + (size_t)node * K + lane8 * 4;
            #pragma unroll
            for (int q = 0; q < NQ; ++q) {
                float4 v = *(const float4*)&xr[q * 32];
                if (RELU_IN) { v.x = fmaxf(v.x, 0.f); v.y = fmaxf(v.y, 0.f);
                               v.z = fmaxf(v.z, 0.f); v.w = fmaxf(v.w, 0.f); }
                sx[q] = v.x; sy[q] = v.y; sz[q] = v.z; sw[q] = v.w;
            }
        }

        // ---- k-quarter phases ----
        #pragma unroll
        for (int q = 0; q < KS; ++q) {
            if (q > 0) {
                __syncthreads();                       // GEMM q-1 done with Wbuf/meanS
                stage20(wtRel + q * 10240, Wbuf, t);   // chunk q
            }
            // write quarter q (hi,lo) planes: lane owns float4 at k lane8*4
            {
                const float vx = sx[q], vy = sy[q], vz = sz[q], vw = sw[q];
                const unsigned short hx = bf16rn(vx), hy = bf16rn(vy), hz = bf16rn(vz), hw = bf16rn(vw);
                short4 hi4, lo4;
                hi4.x = (short)hx; hi4.y = (short)hy; hi4.z = (short)hz; hi4.w = (short)hw;
                lo4.x = (short)bf16rn(vx - bf16tof(hx));
                lo4.y = (short)bf16rn(vy - bf16tof(hy));
                lo4.z = (short)bf16rn(vz - bf16tof(hz));
                lo4.w = (short)bf16rn(vw - bf16tof(hw));
                const int kb = team * QSs + lane8 * 4;
                *(short4*)&meanS[kb]       = hi4;
                *(short4*)&meanS[PSq + kb] = lo4;
            }
            __syncthreads();   // drains vmcnt (Wbuf chunk q landed) + lgkm (meanS)

            // B-fragments from staged Wbuf
            short8 bhi[2], blo[2];
            #pragma unroll
            for (int ct = 0; ct < 2; ++ct) {
                const int col = wv * 32 + ct * 16 + (l & 15);
                bhi[ct] = *(const short8*)&Wbuf[       col * 40 + q8];
                blo[ct] = *(const short8*)&Wbuf[5120 + col * 40 + q8];
            }

            // GEMM quarter q: 3-product bf16 split MFMA (2 rt x 2 ct)
            #pragma unroll
            for (int rt = 0; rt < 2; ++rt) {
                const int row = rt * 16 + (l & 15);
                const int ka  = row * QSs + q8;
                const short8 a0 = *(const short8*)&meanS[ka];
                const short8 a1 = *(const short8*)&meanS[PSq + ka];
                #pragma unroll
                for (int ct = 0; ct < 2; ++ct) {
                    acc[rt][ct] = __builtin_amdgcn_mfma_f32_16x16x32_bf16(a0, bhi[ct], acc[rt][ct], 0, 0, 0);
                    acc[rt][ct] = __builtin_amdgcn_mfma_f32_16x16x32_bf16(a0, blo[ct], acc[rt][ct], 0, 0, 0);
                    acc[rt][ct] = __builtin_amdgcn_mfma_f32_16x16x32_bf16(a1, bhi[ct], acc[rt][ct], 0, 0, 0);
                }
            }
        }
    }

    // ---- combine partials: atomicAdd into zero-initialized H ----
    // D layout: col=lane&15, row=(lane>>4)*4+reg
    #pragma unroll
    for (int rt = 0; rt < 2; ++rt) {
        #pragma unroll
        for (int reg = 0; reg < 4; ++reg) {
            const int n = n0 + rt * 16 + (l >> 4) * 4 + reg;
            if (n < nnodes) {
                #pragma unroll
                for (int ct = 0; ct < 2; ++ct) {
                    atomicAdd(&H[(size_t)n * 128 + wv * 32 + ct * 16 + (l & 15)],
                              acc[rt][ct][reg]);
                }
            }
        }
    }
}

// ---------------------------------------------------------------------------
// DistMult decoder: one 64-lane wave per batch element (h2 has no relu)
// ---------------------------------------------------------------------------
__global__ void decoder_kernel(const float* __restrict__ H, const float* __restrict__ rel_emb,
                               const int* __restrict__ head, const int* __restrict__ tail,
                               const int* __restrict__ rt, float* __restrict__ out, int B) {
    const int idx  = blockIdx.x * blockDim.x + threadIdx.x;
    const int b    = idx >> 6;
    const int lane = idx & 63;
    if (b >= B) return;
    const float* hp = H + (size_t)head[b] * 128;
    const float* tp = H + (size_t)tail[b] * 128;
    const float* rp = rel_emb + (size_t)rt[b] * 128;
    double s = 0.0;
    #pragma unroll
    for (int c = 0; c < 2; ++c) {
        const int k = lane + c * 64;
        s += (double)hp[k] * (double)rp[k] * (double)tp[k];
    }
    for (int o = 32; o > 0; o >>= 1) s += __shfl_down(s, o);
    if (lane == 0) out[b] = (float)s;
}

// ---------------------------------------------------------------------------

extern "C" void kernel_launch(void* const* d_in, const int* in_sizes, int n_in,
                              void* d_out, int out_size, void* d_ws, size_t ws_size,
                              hipStream_t stream) {
    const int*   edge_index = (const int*)d_in[0];   // [2][E]
    const int*   edge_type  = (const int*)d_in[1];   // [E]
    const int*   head       = (const int*)d_in[2];   // [B]
    const int*   tail       = (const int*)d_in[3];   // [B]
    const int*   rtyp       = (const int*)d_in[4];   // [B]
    const float* node_emb   = (const float*)d_in[5]; // [N][64]
    const float* W1         = (const float*)d_in[6]; // [20][64][128]
    const float* root1      = (const float*)d_in[7]; // [64][128]
    const float* b1         = (const float*)d_in[8]; // [128]
    const float* W2         = (const float*)d_in[9]; // [20][128][128]
    const float* root2      = (const float*)d_in[10];// [128][128]
    const float* b2         = (const float*)d_in[11];// [128]
    const float* rel_emb    = (const float*)d_in[12];// [20][128]
    float* out = (float*)d_out;

    const int E = in_sizes[1];
    const int B = in_sizes[2];
    const int* src = edge_index;
    const int* dst = edge_index + E;

    // workspace carve (all 256B-aligned)
    char* ws = (char*)d_ws;
    size_t o = 0;
    auto carve = [&](size_t bytes) { char* p = ws + o; o += (bytes + 255) & ~size_t(255); return p; };
    int*   off     = (int*)carve(sizeof(int) * NSEG);        // 4 MB
    int*   cnt     = (int*)carve(sizeof(int) * NSEG);        // 4 MB
    int*   csr_src = (int*)carve(sizeof(int) * (size_t)E);   // 6.4 MB
    int*   bsum    = (int*)carve(sizeof(int) * 1024);
    float* h1      = (float*)carve(sizeof(float) * (size_t)NNODES * DHID); // 25.6 MB
    float* h2      = (float*)carve(sizeof(float) * (size_t)NNODES * DHID); // 25.6 MB
    short* Wt1     = (short*)carve(sizeof(short) * (size_t)(NREL + 1) * 2 * 10240); // 1.72 MB
    short* Wt2     = (short*)carve(sizeof(short) * (size_t)(NREL + 1) * 4 * 10240); // 3.44 MB
    (void)ws_size;

    const int NCHUNK = (NSEG + 1023) / 1024;   // 977

    // W prep (independent of CSR; cheap)
    {
        const int tot1 = (NREL + 1) * 128 * DEMB;
        const int tot2 = (NREL + 1) * 128 * DHID;
        prep_w<DEMB><<<(tot1 + 255) / 256, 256, 0, stream>>>(W1, root1, Wt1);
        prep_w<DHID><<<(tot2 + 255) / 256, 256, 0, stream>>>(W2, root2, Wt2);
    }

    // CSR build
    hipMemsetAsync(cnt, 0, sizeof(int) * NSEG, stream);
    hist_kernel<<<2048, 256, 0, stream>>>(dst, edge_type, E, cnt);
    scan_partial<<<NCHUNK, 256, 0, stream>>>(cnt, bsum, NSEG);
    scan_bsums<<<1, 1024, 0, stream>>>(bsum, NCHUNK);
    scan_final<<<NCHUNK, 256, 0, stream>>>(cnt, bsum, off, NSEG);
    place_kernel<<<2048, 256, 0, stream>>>(src, dst, edge_type, E, off, csr_src);

    // zero-init layer outputs (atomic accumulation targets)
    hipMemsetAsync(h1, 0, sizeof(float) * (size_t)NNODES * DHID, stream);
    hipMemsetAsync(h2, 0, sizeof(float) * (size_t)NNODES * DHID, stream);

    // layers: 32 nodes/block, 256 threads, relation-split x2 (gridDim.y)
    const dim3 LGRID((NNODES + 31) / 32, 2);   // 1563 x 2 = 3126 blocks
    rgcn_layer_kernel<DEMB, false><<<LGRID, 256, 0, stream>>>(node_emb, Wt1, b1,
                                                              off, cnt, csr_src, h1, NNODES);
    rgcn_layer_kernel<DHID, true ><<<LGRID, 256, 0, stream>>>(h1, Wt2, b2,
                                                              off, cnt, csr_src, h2, NNODES);

    // decoder
    decoder_kernel<<<(B * 64 + 255) / 256, 256, 0, stream>>>(h2, rel_emb, head, tail, rtyp, out, B);
}